// Round 20
// baseline (78.179 us; speedup 1.0000x reference)
//
#include <hip/hip_runtime.h>
#include <math.h>

#define HEADS 4
#define HD    64
#define CCH   256
#define NB    4
#define HH    48
#define WW    48
#define NN    (HH*WW)            // 2304
#define EPSBN 1e-5f
#define KSCL  0.18033688f        // 0.125 * log2(e)  (folded into K weights/bias)
#define BCN   (NB*CCH*NN)        // 2,359,296 elements
#define NSP   4                  // kv splits

typedef unsigned short ushort_t;
typedef __attribute__((ext_vector_type(8))) short bfrag;    // 8 bf16 = 4 VGPR
typedef __attribute__((ext_vector_type(4))) float f32x4;    // 16x16 C/D
typedef __attribute__((ext_vector_type(16))) float f32x16;  // 32x32 C/D

#define MFMA   __builtin_amdgcn_mfma_f32_16x16x32_bf16
#define MFMA32 __builtin_amdgcn_mfma_f32_32x32x16_bf16

static __device__ __forceinline__ unsigned cvtpk(float lo, float hi) {
    unsigned r;
    asm("v_cvt_pk_bf16_f32 %0, %1, %2" : "=v"(r) : "v"(lo), "v"(hi));
    return r;
}
static __device__ __forceinline__ float fexp2(float x) {
    float r;
    asm("v_exp_f32 %0, %1" : "=v"(r) : "v"(x));
    return r;
}
static __device__ __forceinline__ float bflo(unsigned u) { return __uint_as_float(u << 16); }
static __device__ __forceinline__ float bfhi(unsigned u) { return __uint_as_float(u & 0xffff0000u); }

static __device__ __forceinline__ void gload16(const void* g, void* l) {
    __builtin_amdgcn_global_load_lds(
        (const __attribute__((address_space(1))) void*)g,
        (__attribute__((address_space(3))) void*)l, 16, 0, 0);
}

static __device__ __forceinline__ ushort_t f2bf(float x) {
    unsigned int u = __float_as_uint(x);
    unsigned int r = (u + 0x7fffu + ((u >> 16) & 1u)) >> 16;   // RNE
    return (ushort_t)r;
}

// ---------------------------------------------------------------------------
// bf16 MFMA 1x1-conv GEMM, 64x64 tile, full K=256, 512 threads (8 waves).
// BN scale folded into weight staging; bias folded in epilogue. No prep pass.
// MODE 0 (q/k/v): z<12 GEMM (which=z>>2); z==12 block(0,0): PE weight fold.
// MODE 1 (proj): T = yt bf16 [b][n][c]; fp32 [b][c][n] -> d_out.
// ---------------------------------------------------------------------------
struct ConvP {
    const float* X0; const float* X1; const float* X2;   // q,k,v fp32
    const ushort_t* T;                                    // yt (MODE 1)
    const float* W[4]; const float* G[4]; const float* Bb[4];
    const float* Mm[4]; const float* Vv[4];
    const float* pew; const float* peg; const float* peb;
    const float* pem; const float* pev;
    ushort_t* pw2; float* pbias;
    ushort_t* qnd; ushort_t* knd; ushort_t* vcn; float* outf;
};

template<int PROJ>
__global__ __launch_bounds__(512)
void conv_gemm(ConvP P)
{
    __shared__ ushort_t Ts[64][264];
    __shared__ ushort_t Ws[64][264];
    const int nt = blockIdx.x, ot = blockIdx.y, z = blockIdx.z;
    const int tid = threadIdx.x;
    if (!PROJ && z == 12) {          // PE fold slice: one working block
        if (nt == 0 && ot == 0 && tid < CCH) {
            int c = tid;
            float s = P.peg[c] * rsqrtf(P.pev[c] + EPSBN);
            for (int tap = 0; tap < 9; ++tap)
                P.pw2[tap * CCH + c] = f2bf(P.pew[c * 9 + tap] * s);
            P.pbias[c] = P.peb[c] - P.pem[c] * s;
        }
        return;
    }
    const int which = PROJ ? 3 : (z >> 2);
    const int b = z & 3;
    const int n0 = nt * 64, o0 = ot * 64;
    const float* Wf  = P.W[which];
    const float* Gf  = P.G[which];
    const float* Bbf = P.Bb[which];
    const float* Mmf = P.Mm[which];
    const float* Vvf = P.Vv[which];
    const float wmul = (which == 1) ? KSCL : 1.0f;

    // stage Ws: fp32 weights * BN scale -> bf16
#pragma unroll
    for (int i = 0; i < 4; ++i) {
        int idx = tid + i * 512;
        int r = idx >> 5, c16 = idx & 31;
        int o = o0 + r;
        float s2 = Gf[o] * rsqrtf(Vvf[o] + EPSBN) * wmul;
        const float* wp = Wf + (size_t)o * CCH + c16 * 8;
        float4 wa = *(const float4*)&wp[0];
        float4 wb = *(const float4*)&wp[4];
        uint4 u;
        u.x = cvtpk(wa.x * s2, wa.y * s2); u.y = cvtpk(wa.z * s2, wa.w * s2);
        u.z = cvtpk(wb.x * s2, wb.y * s2); u.w = cvtpk(wb.z * s2, wb.w * s2);
        *(uint4*)&Ws[r][c16 * 8] = u;
    }
    if (!PROJ) {
        // Ts: fp32 [c][n] -> bf16 [n][c] transpose
        const float* Xf = (which == 0) ? P.X0 : (which == 1) ? P.X1 : P.X2;
        const float* Xb = Xf + (size_t)b * CCH * NN + n0;
        const int n = tid & 63;
#pragma unroll
        for (int p = 0; p < 4; ++p) {
            int c0 = (tid >> 6) * 8 + p * 64;
            const float* src = Xb + (size_t)c0 * NN + n;
            float vv[8];
#pragma unroll
            for (int j = 0; j < 8; ++j) vv[j] = src[(size_t)j * NN];
            uint4 u;
            u.x = cvtpk(vv[0], vv[1]); u.y = cvtpk(vv[2], vv[3]);
            u.z = cvtpk(vv[4], vv[5]); u.w = cvtpk(vv[6], vv[7]);
            *(uint4*)&Ts[n][c0] = u;
        }
    } else {
        const ushort_t* Tsrc = P.T + ((size_t)b * NN + n0) * CCH;
#pragma unroll
        for (int i = 0; i < 4; ++i) {
            int idx = tid + i * 512;
            int r = idx >> 5, c16 = idx & 31;
            *(uint4*)&Ts[r][c16 * 8] = *(const uint4*)&Tsrc[(size_t)r * CCH + c16 * 8];
        }
    }
    __syncthreads();
    const int wv = tid >> 6, lane = tid & 63, lr = lane & 15, lg = lane >> 4;
    const int qn = (wv >> 1) * 16, qo = (wv & 1) * 32;
    f32x4 acc[2];
    acc[0] = (f32x4){0.f, 0.f, 0.f, 0.f};
    acc[1] = (f32x4){0.f, 0.f, 0.f, 0.f};

    if (!PROJ && which < 2) {
#pragma unroll
        for (int k8 = 0; k8 < 8; ++k8) {
            const int kc = k8 * 32 + lg * 8;
            bfrag ta  = *(const bfrag*)&Ts[qn + lr][kc];
            bfrag wa0 = *(const bfrag*)&Ws[qo + lr][kc];
            bfrag wa1 = *(const bfrag*)&Ws[qo + 16 + lr][kc];
            acc[0] = MFMA(ta, wa0, acc[0], 0, 0, 0);
            acc[1] = MFMA(ta, wa1, acc[1], 0, 0, 0);
        }
    } else {
#pragma unroll
        for (int k8 = 0; k8 < 8; ++k8) {
            const int kc = k8 * 32 + lg * 8;
            bfrag ta  = *(const bfrag*)&Ts[qn + lr][kc];
            bfrag wa0 = *(const bfrag*)&Ws[qo + lr][kc];
            bfrag wa1 = *(const bfrag*)&Ws[qo + 16 + lr][kc];
            acc[0] = MFMA(wa0, ta, acc[0], 0, 0, 0);
            acc[1] = MFMA(wa1, ta, acc[1], 0, 0, 0);
        }
    }

    __syncthreads();   // Ts/Ws dead; overlay epilogue staging
    if (!PROJ && which < 2) {
        ushort_t (*Ot)[72] = (ushort_t(*)[72])Ts;
        float bv[2];
#pragma unroll
        for (int j = 0; j < 2; ++j) {
            int o = o0 + qo + j * 16 + lr;
            float s = Gf[o] * rsqrtf(Vvf[o] + EPSBN);
            bv[j] = (Bbf[o] - Mmf[o] * s) * wmul;
        }
#pragma unroll
        for (int j = 0; j < 2; ++j)
#pragma unroll
            for (int r = 0; r < 4; ++r)
                Ot[qn + lg * 4 + r][qo + j * 16 + lr] = f2bf(acc[j][r] + bv[j]);
        __syncthreads();
        ushort_t* out = (which == 0) ? P.qnd : P.knd;
        {
            int r = tid >> 3, sg = tid & 7;
            *(uint4*)&out[(((size_t)b * HEADS + ot) * NN + n0 + r) * HD + sg * 8] =
                *(const uint4*)&Ot[r][sg * 8];
        }
    } else if (!PROJ) {
        ushort_t (*Ot)[72] = (ushort_t(*)[72])Ts;
#pragma unroll
        for (int j = 0; j < 2; ++j)
#pragma unroll
            for (int r = 0; r < 4; ++r) {
                int o = o0 + qo + j * 16 + lg * 4 + r;
                float s = Gf[o] * rsqrtf(Vvf[o] + EPSBN);
                float bv = Bbf[o] - Mmf[o] * s;
                Ot[qo + j * 16 + lg * 4 + r][qn + lr] = f2bf(acc[j][r] + bv);
            }
        __syncthreads();
        {
            int r = tid >> 3, sg = tid & 7;
            *(uint4*)&P.vcn[((size_t)b * CCH + o0 + r) * NN + n0 + sg * 8] =
                *(const uint4*)&Ot[r][sg * 8];
        }
    } else {
        float (*Of)[68] = (float(*)[68])Ts;
#pragma unroll
        for (int j = 0; j < 2; ++j)
#pragma unroll
            for (int r = 0; r < 4; ++r) {
                int o = o0 + qo + j * 16 + lg * 4 + r;
                float s = Gf[o] * rsqrtf(Vvf[o] + EPSBN);
                float bv = Bbf[o] - Mmf[o] * s;
                Of[qo + j * 16 + lg * 4 + r][qn + lr] = acc[j][r] + bv;
            }
        __syncthreads();
#pragma unroll
        for (int i = 0; i < 2; ++i) {
            int idx = tid + i * 512;
            int r = idx >> 4, c4 = idx & 15;
            *(float4*)&P.outf[((size_t)b * CCH + o0 + r) * NN + n0 + c4 * 4] =
                *(const float4*)&Of[r][c4 * 4];
        }
    }
}

// ---------------------------------------------------------------------------
// MFMA flash attention, 32x32x16 shape: 4 waves x 64 q (2 q-blocks sharing
// every K/V fragment read), Bc=64, kv-split x4. Single barrier/tile; raw
// v_exp_f32; P in regs via cvt_pk + v_permlane32_swap. LDS 40KB (32 loop +
// 40 epilogue overlay).
// ---------------------------------------------------------------------------
__global__ __launch_bounds__(256, 2)
void attn_kernel(const ushort_t* __restrict__ Qnd,   // bf16 [b][h][n][d]
                 const ushort_t* __restrict__ Knd,   // bf16 [b][h][n][d] *KSCL
                 const ushort_t* __restrict__ Vcn,   // bf16 [b][c][n]
                 ushort_t* __restrict__ Op,          // bf16 [4][b][n][c]
                 float* __restrict__ Larr)           // fp32 [4][16][NN]
{
    __shared__ __align__(16) char smem[40960];
    // loop: K2 @0 [2][8192]sw, V2 @16384 [2][8192]sw. epilogue: [256][40] u32.

    const int tid = threadIdx.x;
    const int lin0 = blockIdx.x + 9 * blockIdx.y + 144 * blockIdx.z;
    const int w    = (lin0 & 7) * 72 + (lin0 >> 3);   // XCD-chunked remap (576=8*72)
    const int qt = w % 9;
    const int bh = (w / 9) & 15;
    const int sp = w / 144;
    const int b = bh >> 2, h = bh & 3;
    const int lane = tid & 63, wv = tid >> 6;
    const int l31 = lane & 31, hi = lane >> 5, l7 = lane & 7;
    const int lrow = lane >> 3, lslot = (lane & 7) ^ lrow;
    const int n0 = qt * 256;
    const size_t ndb = (size_t)(b * HEADS + h) * NN * HD;
    const size_t cnb = ((size_t)b * CCH + h * HD) * NN;

    const char* kgp = (const char*)(Knd + ndb) + (size_t)(sp * 576 + wv * 16 + lrow) * 128 + lslot * 16;
    const char* vgp = (const char*)(Vcn + cnb + sp * 576) + (size_t)(wv * 16 + lrow) * (NN * 2) + lslot * 16;
    char* kls = smem + wv * 2048;
    char* vls = smem + 16384 + wv * 2048;

#define STAGE(buf, t) do { \
    const char* kp_ = kgp + (size_t)(t) * 8192; \
    const char* vp_ = vgp + (size_t)(t) * 128; \
    char* kd_ = kls + (buf) * 8192; \
    char* vd_ = vls + (buf) * 8192; \
    gload16(kp_,              kd_); \
    gload16(kp_ + 1024,       kd_ + 1024); \
    gload16(vp_,              vd_); \
    gload16(vp_ + 8 * (NN*2), vd_ + 1024); \
} while (0)

    // Q B-fragments: 64 q/wave (2 q-blocks of 32); frag ds covers d=ds*16+hi*8..+7
    bfrag qb[2][4];
    {
#pragma unroll
        for (int qc = 0; qc < 2; ++qc) {
            const ushort_t* qbase = Qnd + ndb
                + (size_t)(n0 + wv * 64 + qc * 32 + l31) * HD + hi * 8;
#pragma unroll
            for (int ds = 0; ds < 4; ++ds)
                qb[qc][ds] = *(const bfrag*)&qbase[ds * 16];
        }
    }

    f32x16 o[2][2];
#pragma unroll
    for (int qc = 0; qc < 2; ++qc)
#pragma unroll
        for (int db = 0; db < 2; ++db)
#pragma unroll
            for (int j = 0; j < 16; ++j) o[qc][db][j] = 0.f;
    float lacc0[2] = {0.f, 0.f}, lacc1[2] = {0.f, 0.f};

    STAGE(0, 0);

    for (int t = 0; t < 9; ++t) {
        const int cur = t & 1;
        asm volatile("s_waitcnt vmcnt(0)" ::: "memory");   // own tile-t loads landed
        __builtin_amdgcn_s_barrier();   // tile-t staged everywhere; buf[cur^1] free
        if (t < 8) STAGE(cur ^ 1, t + 1);                  // prefetch flies over compute
        const char* Kb = smem + cur * 8192;
        const char* Vb = smem + 16384 + cur * 8192;

        // QK (K fragments shared across both q-blocks) + v_exp + in-reg P
        bfrag pf[2][4];
#pragma unroll
        for (int kb = 0; kb < 2; ++kb) {
            f32x16 s0, s1;
#pragma unroll
            for (int j = 0; j < 16; ++j) { s0[j] = 0.f; s1[j] = 0.f; }
            __builtin_amdgcn_s_setprio(1);
#pragma unroll
            for (int ds = 0; ds < 4; ++ds) {
                const char* ka_p = Kb + (kb * 32 + l31) * 128 + (((2 * ds + hi) ^ l7) << 4);
                bfrag ka = *(const bfrag*)ka_p;
                s0 = MFMA32(ka, qb[0][ds], s0, 0, 0, 0);
                s1 = MFMA32(ka, qb[1][ds], s1, 0, 0, 0);
            }
            __builtin_amdgcn_s_setprio(0);
#pragma unroll
            for (int qc = 0; qc < 2; ++qc) {
                float e[16];
#pragma unroll
                for (int j = 0; j < 16; ++j) e[j] = fexp2(qc ? s1[j] : s0[j]);
#pragma unroll
                for (int j = 0; j < 8; ++j) { lacc0[qc] += e[2 * j]; lacc1[qc] += e[2 * j + 1]; }
                unsigned u[4][2];
#pragma unroll
                for (int g = 0; g < 4; ++g) {
                    u[g][0] = cvtpk(e[4 * g + 0], e[4 * g + 1]);
                    u[g][1] = cvtpk(e[4 * g + 2], e[4 * g + 3]);
                }
#pragma unroll
                for (int ks = 0; ks < 2; ++ks) {
                    asm("v_permlane32_swap_b32 %0, %1" : "+v"(u[2*ks][0]), "+v"(u[2*ks+1][0]));
                    asm("v_permlane32_swap_b32 %0, %1" : "+v"(u[2*ks][1]), "+v"(u[2*ks+1][1]));
                    uint4 fw = { u[2*ks][0], u[2*ks][1], u[2*ks+1][0], u[2*ks+1][1] };
                    pf[qc][kb * 2 + ks] = *(const bfrag*)&fw;
                }
            }
        }

        // PV (V fragments shared across both q-blocks)
        __builtin_amdgcn_s_setprio(1);
#pragma unroll
        for (int db = 0; db < 2; ++db)
#pragma unroll
            for (int ks = 0; ks < 4; ++ks) {
                const char* va_p = Vb + (db * 32 + l31) * 128 + (((2 * ks + hi) ^ l7) << 4);
                bfrag va = *(const bfrag*)va_p;
                o[0][db] = MFMA32(va, pf[0][ks], o[0][db], 0, 0, 0);
                o[1][db] = MFMA32(va, pf[1][ks], o[1][db], 0, 0, 0);
            }
        __builtin_amdgcn_s_setprio(0);
    }
#undef STAGE
    __builtin_amdgcn_s_barrier();   // all compute done before smem overlay

    // l: in-lane partial + cross-half combine (both halves share q = l31)
#pragma unroll
    for (int qc = 0; qc < 2; ++qc) {
        float lacc = lacc0[qc] + lacc1[qc];
        lacc += __shfl_xor(lacc, 32);
        if (hi == 0)
            Larr[(size_t)(sp * 16 + bh) * NN + n0 + wv * 64 + qc * 32 + l31] = lacc;
    }

    // epilogue: pack O' bf16, transpose via LDS [256][40] u32, coalesced stores
    unsigned (*Osb)[40] = (unsigned(*)[40])smem;
#pragma unroll
    for (int qc = 0; qc < 2; ++qc) {
        int row = wv * 64 + qc * 32 + l31;
#pragma unroll
        for (int db = 0; db < 2; ++db)
#pragma unroll
            for (int g = 0; g < 4; ++g) {
                uint2 pk;
                pk.x = cvtpk(o[qc][db][4 * g + 0], o[qc][db][4 * g + 1]);
                pk.y = cvtpk(o[qc][db][4 * g + 2], o[qc][db][4 * g + 3]);
                *(uint2*)&Osb[row][16 * db + 4 * g + 2 * hi] = pk;
            }
    }
    __syncthreads();
    ushort_t* opb = Op + (size_t)sp * BCN + ((size_t)b * NN + n0) * CCH + h * HD;
    for (int idx = tid; idx < 2048; idx += 256) {
        int n = idx >> 3, s4 = idx & 7;
        *(uint4*)&opb[(size_t)n * CCH + s4 * 8] = *(const uint4*)&Osb[n][s4 * 4];
    }
}

// ---------------------------------------------------------------------------
// fuse: sum kv-splits (bf16 O') + depthwise 3x3 BN (tap-major bf16 pw2)
// -> bf16 [b][n][c]
// ---------------------------------------------------------------------------
__global__ __launch_bounds__(256)
void fuse_kernel(const ushort_t* __restrict__ Op, const float* __restrict__ Larr,
                 const ushort_t* __restrict__ Qnd,
                 const ushort_t* __restrict__ pw2, const float* __restrict__ pbias,
                 ushort_t* __restrict__ yt)
{
    const int tid = threadIdx.x;
    const int b  = blockIdx.x / 288;
    const int n0 = (blockIdx.x % 288) * 8;
    const int c8 = tid & 31, ns = tid >> 5;
    const int n  = n0 + ns;
    const int h  = c8 >> 3, c0 = c8 * 8;

    const ushort_t* o0p = Op + ((size_t)b * NN + n) * CCH + c0;
    float acc[8] = {0.f, 0.f, 0.f, 0.f, 0.f, 0.f, 0.f, 0.f};
#pragma unroll
    for (int s = 0; s < NSP; ++s) {
        uint4 u = *(const uint4*)&o0p[(size_t)s * BCN];
        acc[0] += bflo(u.x); acc[1] += bfhi(u.x);
        acc[2] += bflo(u.y); acc[3] += bfhi(u.y);
        acc[4] += bflo(u.z); acc[5] += bfhi(u.z);
        acc[6] += bflo(u.w); acc[7] += bfhi(u.w);
    }
    int mi = (b * HEADS + h) * NN + n;
    float ls = 0.f;
#pragma unroll
    for (int s = 0; s < NSP; ++s) ls += Larr[(size_t)s * 16 * NN + mi];
    float rinv = 1.0f / ls;
#pragma unroll
    for (int j = 0; j < 8; ++j) acc[j] *= rinv;

    const int x = n % WW, y = n / WW;
    const ushort_t* qb = Qnd + (size_t)(b * HEADS + h) * NN * HD + (c8 & 7) * 8;
#pragma unroll
    for (int ky = 0; ky < 3; ++ky) {
        int yy = y + ky - 1;
        if (yy < 0 || yy >= HH) continue;
#pragma unroll
        for (int kx = 0; kx < 3; ++kx) {
            int xx = x + kx - 1;
            if (xx < 0 || xx >= WW) continue;
            int np = yy * WW + xx;
            uint4 qv = *(const uint4*)&qb[(size_t)np * HD];
            uint4 w4 = *(const uint4*)&pw2[(ky * 3 + kx) * CCH + c0];
            acc[0] += bflo(qv.x) * bflo(w4.x); acc[1] += bfhi(qv.x) * bfhi(w4.x);
            acc[2] += bflo(qv.y) * bflo(w4.y); acc[3] += bfhi(qv.y) * bfhi(w4.y);
            acc[4] += bflo(qv.z) * bflo(w4.z); acc[5] += bfhi(qv.z) * bfhi(w4.z);
            acc[6] += bflo(qv.w) * bflo(w4.w); acc[7] += bfhi(qv.w) * bfhi(w4.w);
        }
    }
    float4 p0 = *(const float4*)&pbias[c0];
    float4 p1 = *(const float4*)&pbias[c0 + 4];
    acc[0] += p0.x; acc[1] += p0.y; acc[2] += p0.z; acc[3] += p0.w;
    acc[4] += p1.x; acc[5] += p1.y; acc[6] += p1.z; acc[7] += p1.w;
    uint4 u;
    u.x = cvtpk(acc[0], acc[1]); u.y = cvtpk(acc[2], acc[3]);
    u.z = cvtpk(acc[4], acc[5]); u.w = cvtpk(acc[6], acc[7]);
    *(uint4*)&yt[((size_t)b * NN + n) * CCH + c0] = u;
}

// ---------------------------------------------------------------------------
extern "C" void kernel_launch(void* const* d_in, const int* in_sizes, int n_in,
                              void* d_out, int out_size, void* d_ws, size_t ws_size,
                              hipStream_t stream) {
    char* ws = (char*)d_ws;
    ushort_t* qnd  = (ushort_t*)(ws + 0);
    ushort_t* knd  = (ushort_t*)(ws + 4718592);
    ushort_t* vcn  = (ushort_t*)(ws + 9437184);
    ushort_t* Op   = (ushort_t*)(ws + 14155776);   // bf16 [4][BCN]
    ushort_t* yt   = (ushort_t*)(ws + 4718592);    // overlays knd after attn
    float*    Larr = (float*)   (ws + 33030144);   // [4][16][NN] fp32
    ushort_t* pw2  = (ushort_t*)(ws + 33619968);   // bf16 [9][256]
    float*    pbias= (float*)   (ws + 33624576);   // fp32 [256]

    ConvP P;
    P.X0 = (const float*)d_in[0];
    P.X1 = (const float*)d_in[1];
    P.X2 = (const float*)d_in[2];
    P.T  = yt;
    P.W[0] = (const float*)d_in[3]; P.W[1] = (const float*)d_in[4];
    P.W[2] = (const float*)d_in[5]; P.W[3] = (const float*)d_in[6];
    P.G[0]  = (const float*)d_in[8];  P.Bb[0] = (const float*)d_in[9];
    P.Mm[0] = (const float*)d_in[10]; P.Vv[0] = (const float*)d_in[11];
    P.G[1]  = (const float*)d_in[12]; P.Bb[1] = (const float*)d_in[13];
    P.Mm[1] = (const float*)d_in[14]; P.Vv[1] = (const float*)d_in[15];
    P.G[2]  = (const float*)d_in[16]; P.Bb[2] = (const float*)d_in[17];
    P.Mm[2] = (const float*)d_in[18]; P.Vv[2] = (const float*)d_in[19];
    P.G[3]  = (const float*)d_in[24]; P.Bb[3] = (const float*)d_in[25];
    P.Mm[3] = (const float*)d_in[26]; P.Vv[3] = (const float*)d_in[27];
    P.pew = (const float*)d_in[7];
    P.peg = (const float*)d_in[20]; P.peb = (const float*)d_in[21];
    P.pem = (const float*)d_in[22]; P.pev = (const float*)d_in[23];
    P.pw2 = pw2; P.pbias = pbias;
    P.qnd = qnd; P.knd = knd; P.vcn = vcn; P.outf = (float*)d_out;

    conv_gemm<0><<<dim3(36, 4, 13), 512, 0, stream>>>(P);

    attn_kernel<<<dim3(9, 16, NSP), 256, 0, stream>>>(qnd, knd, vcn, Op, Larr);

    fuse_kernel<<<1152, 256, 0, stream>>>(Op, Larr, qnd, pw2, pbias, yt);

    conv_gemm<1><<<dim3(36, 4, 4), 512, 0, stream>>>(P);
}

// Round 21
// 76.587 us; speedup vs baseline: 1.0208x; 1.0208x over previous
//
#include <hip/hip_runtime.h>
#include <math.h>

#define HEADS 4
#define HD    64
#define CCH   256
#define NB    4
#define HH    48
#define WW    48
#define NN    (HH*WW)            // 2304
#define EPSBN 1e-5f
#define KSCL  0.18033688f        // 0.125 * log2(e)  (folded into K weights/bias)
#define BCN   (NB*CCH*NN)        // 2,359,296 elements
#define NSP   4                  // kv splits

typedef unsigned short ushort_t;
typedef __attribute__((ext_vector_type(8))) short bfrag;    // 8 bf16 = 4 VGPR
typedef __attribute__((ext_vector_type(4))) float f32x4;    // 16x16 C/D
typedef __attribute__((ext_vector_type(16))) float f32x16;  // 32x32 C/D

#define MFMA   __builtin_amdgcn_mfma_f32_16x16x32_bf16
#define MFMA32 __builtin_amdgcn_mfma_f32_32x32x16_bf16

static __device__ __forceinline__ unsigned cvtpk(float lo, float hi) {
    unsigned r;
    asm("v_cvt_pk_bf16_f32 %0, %1, %2" : "=v"(r) : "v"(lo), "v"(hi));
    return r;
}
static __device__ __forceinline__ float fexp2(float x) {
    float r;
    asm("v_exp_f32 %0, %1" : "=v"(r) : "v"(x));
    return r;
}
static __device__ __forceinline__ float bflo(unsigned u) { return __uint_as_float(u << 16); }
static __device__ __forceinline__ float bfhi(unsigned u) { return __uint_as_float(u & 0xffff0000u); }

static __device__ __forceinline__ void gload16(const void* g, void* l) {
    __builtin_amdgcn_global_load_lds(
        (const __attribute__((address_space(1))) void*)g,
        (__attribute__((address_space(3))) void*)l, 16, 0, 0);
}

static __device__ __forceinline__ ushort_t f2bf(float x) {
    unsigned int u = __float_as_uint(x);
    unsigned int r = (u + 0x7fffu + ((u >> 16) & 1u)) >> 16;   // RNE
    return (ushort_t)r;
}

// ---------------------------------------------------------------------------
// bf16 MFMA 1x1-conv GEMM, 64x64 tile, full K=256, 512 threads (8 waves).
// BN scale folded into weight staging; bias folded in epilogue. No prep pass.
// MODE 0 (q/k/v): z<12 GEMM (which=z>>2); z==12 block(0,0): PE weight fold.
// MODE 1 (proj): T = yt bf16 [b][n][c]; fp32 [b][c][n] -> d_out.
// ---------------------------------------------------------------------------
struct ConvP {
    const float* X0; const float* X1; const float* X2;   // q,k,v fp32
    const ushort_t* T;                                    // yt (MODE 1)
    const float* W[4]; const float* G[4]; const float* Bb[4];
    const float* Mm[4]; const float* Vv[4];
    const float* pew; const float* peg; const float* peb;
    const float* pem; const float* pev;
    ushort_t* pw2; float* pbias;
    ushort_t* qnd; ushort_t* knd; ushort_t* vcn; float* outf;
};

template<int PROJ>
__global__ __launch_bounds__(512)
void conv_gemm(ConvP P)
{
    __shared__ ushort_t Ts[64][264];
    __shared__ ushort_t Ws[64][264];
    const int nt = blockIdx.x, ot = blockIdx.y, z = blockIdx.z;
    const int tid = threadIdx.x;
    if (!PROJ && z == 12) {          // PE fold slice: one working block
        if (nt == 0 && ot == 0 && tid < CCH) {
            int c = tid;
            float s = P.peg[c] * rsqrtf(P.pev[c] + EPSBN);
            for (int tap = 0; tap < 9; ++tap)
                P.pw2[tap * CCH + c] = f2bf(P.pew[c * 9 + tap] * s);
            P.pbias[c] = P.peb[c] - P.pem[c] * s;
        }
        return;
    }
    const int which = PROJ ? 3 : (z >> 2);
    const int b = z & 3;
    const int n0 = nt * 64, o0 = ot * 64;
    const float* Wf  = P.W[which];
    const float* Gf  = P.G[which];
    const float* Bbf = P.Bb[which];
    const float* Mmf = P.Mm[which];
    const float* Vvf = P.Vv[which];
    const float wmul = (which == 1) ? KSCL : 1.0f;

    // stage Ws: fp32 weights * BN scale -> bf16
#pragma unroll
    for (int i = 0; i < 4; ++i) {
        int idx = tid + i * 512;
        int r = idx >> 5, c16 = idx & 31;
        int o = o0 + r;
        float s2 = Gf[o] * rsqrtf(Vvf[o] + EPSBN) * wmul;
        const float* wp = Wf + (size_t)o * CCH + c16 * 8;
        float4 wa = *(const float4*)&wp[0];
        float4 wb = *(const float4*)&wp[4];
        uint4 u;
        u.x = cvtpk(wa.x * s2, wa.y * s2); u.y = cvtpk(wa.z * s2, wa.w * s2);
        u.z = cvtpk(wb.x * s2, wb.y * s2); u.w = cvtpk(wb.z * s2, wb.w * s2);
        *(uint4*)&Ws[r][c16 * 8] = u;
    }
    if (!PROJ) {
        // Ts: fp32 [c][n] -> bf16 [n][c] transpose
        const float* Xf = (which == 0) ? P.X0 : (which == 1) ? P.X1 : P.X2;
        const float* Xb = Xf + (size_t)b * CCH * NN + n0;
        const int n = tid & 63;
#pragma unroll
        for (int p = 0; p < 4; ++p) {
            int c0 = (tid >> 6) * 8 + p * 64;
            const float* src = Xb + (size_t)c0 * NN + n;
            float vv[8];
#pragma unroll
            for (int j = 0; j < 8; ++j) vv[j] = src[(size_t)j * NN];
            uint4 u;
            u.x = cvtpk(vv[0], vv[1]); u.y = cvtpk(vv[2], vv[3]);
            u.z = cvtpk(vv[4], vv[5]); u.w = cvtpk(vv[6], vv[7]);
            *(uint4*)&Ts[n][c0] = u;
        }
    } else {
        const ushort_t* Tsrc = P.T + ((size_t)b * NN + n0) * CCH;
#pragma unroll
        for (int i = 0; i < 4; ++i) {
            int idx = tid + i * 512;
            int r = idx >> 5, c16 = idx & 31;
            *(uint4*)&Ts[r][c16 * 8] = *(const uint4*)&Tsrc[(size_t)r * CCH + c16 * 8];
        }
    }
    __syncthreads();
    const int wv = tid >> 6, lane = tid & 63, lr = lane & 15, lg = lane >> 4;
    const int qn = (wv >> 1) * 16, qo = (wv & 1) * 32;
    f32x4 acc[2];
    acc[0] = (f32x4){0.f, 0.f, 0.f, 0.f};
    acc[1] = (f32x4){0.f, 0.f, 0.f, 0.f};

    if (!PROJ && which < 2) {
#pragma unroll
        for (int k8 = 0; k8 < 8; ++k8) {
            const int kc = k8 * 32 + lg * 8;
            bfrag ta  = *(const bfrag*)&Ts[qn + lr][kc];
            bfrag wa0 = *(const bfrag*)&Ws[qo + lr][kc];
            bfrag wa1 = *(const bfrag*)&Ws[qo + 16 + lr][kc];
            acc[0] = MFMA(ta, wa0, acc[0], 0, 0, 0);
            acc[1] = MFMA(ta, wa1, acc[1], 0, 0, 0);
        }
    } else {
#pragma unroll
        for (int k8 = 0; k8 < 8; ++k8) {
            const int kc = k8 * 32 + lg * 8;
            bfrag ta  = *(const bfrag*)&Ts[qn + lr][kc];
            bfrag wa0 = *(const bfrag*)&Ws[qo + lr][kc];
            bfrag wa1 = *(const bfrag*)&Ws[qo + 16 + lr][kc];
            acc[0] = MFMA(wa0, ta, acc[0], 0, 0, 0);
            acc[1] = MFMA(wa1, ta, acc[1], 0, 0, 0);
        }
    }

    __syncthreads();   // Ts/Ws dead; overlay epilogue staging
    if (!PROJ && which < 2) {
        ushort_t (*Ot)[72] = (ushort_t(*)[72])Ts;
        float bv[2];
#pragma unroll
        for (int j = 0; j < 2; ++j) {
            int o = o0 + qo + j * 16 + lr;
            float s = Gf[o] * rsqrtf(Vvf[o] + EPSBN);
            bv[j] = (Bbf[o] - Mmf[o] * s) * wmul;
        }
#pragma unroll
        for (int j = 0; j < 2; ++j)
#pragma unroll
            for (int r = 0; r < 4; ++r)
                Ot[qn + lg * 4 + r][qo + j * 16 + lr] = f2bf(acc[j][r] + bv[j]);
        __syncthreads();
        ushort_t* out = (which == 0) ? P.qnd : P.knd;
        {
            int r = tid >> 3, sg = tid & 7;
            *(uint4*)&out[(((size_t)b * HEADS + ot) * NN + n0 + r) * HD + sg * 8] =
                *(const uint4*)&Ot[r][sg * 8];
        }
    } else if (!PROJ) {
        ushort_t (*Ot)[72] = (ushort_t(*)[72])Ts;
#pragma unroll
        for (int j = 0; j < 2; ++j)
#pragma unroll
            for (int r = 0; r < 4; ++r) {
                int o = o0 + qo + j * 16 + lg * 4 + r;
                float s = Gf[o] * rsqrtf(Vvf[o] + EPSBN);
                float bv = Bbf[o] - Mmf[o] * s;
                Ot[qo + j * 16 + lg * 4 + r][qn + lr] = f2bf(acc[j][r] + bv);
            }
        __syncthreads();
        {
            int r = tid >> 3, sg = tid & 7;
            *(uint4*)&P.vcn[((size_t)b * CCH + o0 + r) * NN + n0 + sg * 8] =
                *(const uint4*)&Ot[r][sg * 8];
        }
    } else {
        float (*Of)[68] = (float(*)[68])Ts;
#pragma unroll
        for (int j = 0; j < 2; ++j)
#pragma unroll
            for (int r = 0; r < 4; ++r) {
                int o = o0 + qo + j * 16 + lg * 4 + r;
                float s = Gf[o] * rsqrtf(Vvf[o] + EPSBN);
                float bv = Bbf[o] - Mmf[o] * s;
                Of[qo + j * 16 + lg * 4 + r][qn + lr] = acc[j][r] + bv;
            }
        __syncthreads();
#pragma unroll
        for (int i = 0; i < 2; ++i) {
            int idx = tid + i * 512;
            int r = idx >> 4, c4 = idx & 15;
            *(float4*)&P.outf[((size_t)b * CCH + o0 + r) * NN + n0 + c4 * 4] =
                *(const float4*)&Of[r][c4 * 4];
        }
    }
}

// ---------------------------------------------------------------------------
// MFMA flash attention, 32x32x16 shape: 4 waves x 32 q, Bc=64, kv-split x4.
// Single barrier/tile; raw v_exp_f32; P in regs via cvt_pk + permlane32_swap.
// ---------------------------------------------------------------------------
__global__ __launch_bounds__(256, 4)
void attn_kernel(const ushort_t* __restrict__ Qnd,   // bf16 [b][h][n][d]
                 const ushort_t* __restrict__ Knd,   // bf16 [b][h][n][d] *KSCL
                 const ushort_t* __restrict__ Vcn,   // bf16 [b][c][n]
                 ushort_t* __restrict__ Op,          // bf16 [4][b][n][c]
                 float* __restrict__ Larr)           // fp32 [4][16][NN]
{
    __shared__ __align__(16) char smem[32768];

    const int tid = threadIdx.x;
    const int lin0 = blockIdx.x + 18 * blockIdx.y + 288 * blockIdx.z;
    const int w    = (lin0 & 7) * 144 + (lin0 >> 3);   // XCD-chunked remap (1152=8*144)
    const int qt = w % 18;
    const int bh = (w / 18) & 15;
    const int sp = w / 288;
    const int b = bh >> 2, h = bh & 3;
    const int lane = tid & 63, wv = tid >> 6;
    const int l31 = lane & 31, hi = lane >> 5, l7 = lane & 7;
    const int lrow = lane >> 3, lslot = (lane & 7) ^ lrow;
    const int n0 = qt * 128;
    const size_t ndb = (size_t)(b * HEADS + h) * NN * HD;
    const size_t cnb = ((size_t)b * CCH + h * HD) * NN;

    const char* kgp = (const char*)(Knd + ndb) + (size_t)(sp * 576 + wv * 16 + lrow) * 128 + lslot * 16;
    const char* vgp = (const char*)(Vcn + cnb + sp * 576) + (size_t)(wv * 16 + lrow) * (NN * 2) + lslot * 16;
    char* kls = smem + wv * 2048;
    char* vls = smem + 16384 + wv * 2048;

#define STAGE(buf, t) do { \
    const char* kp_ = kgp + (size_t)(t) * 8192; \
    const char* vp_ = vgp + (size_t)(t) * 128; \
    char* kd_ = kls + (buf) * 8192; \
    char* vd_ = vls + (buf) * 8192; \
    gload16(kp_,              kd_); \
    gload16(kp_ + 1024,       kd_ + 1024); \
    gload16(vp_,              vd_); \
    gload16(vp_ + 8 * (NN*2), vd_ + 1024); \
} while (0)

    // Q B-fragments: 32 q/wave, q = n0 + wv*32 + l31; frag ds covers d=ds*16+hi*8..+7
    bfrag qb[4];
    {
        const ushort_t* qbase = Qnd + ndb + (size_t)(n0 + wv * 32 + l31) * HD + hi * 8;
#pragma unroll
        for (int ds = 0; ds < 4; ++ds)
            qb[ds] = *(const bfrag*)&qbase[ds * 16];
    }

    f32x16 o[2];
#pragma unroll
    for (int db = 0; db < 2; ++db)
#pragma unroll
        for (int j = 0; j < 16; ++j) o[db][j] = 0.f;
    float lacc0 = 0.f, lacc1 = 0.f;

    STAGE(0, 0);

    for (int t = 0; t < 9; ++t) {
        const int cur = t & 1;
        asm volatile("s_waitcnt vmcnt(0)" ::: "memory");   // own tile-t loads landed
        __builtin_amdgcn_s_barrier();   // tile-t staged everywhere; buf[cur^1] free
        if (t < 8) STAGE(cur ^ 1, t + 1);                  // prefetch flies over compute
        const char* Kb = smem + cur * 8192;
        const char* Vb = smem + 16384 + cur * 8192;

        // QK + raw v_exp + in-register P fragments
        bfrag pf[4];
#pragma unroll
        for (int kb = 0; kb < 2; ++kb) {
            f32x16 s;
#pragma unroll
            for (int j = 0; j < 16; ++j) s[j] = 0.f;
            __builtin_amdgcn_s_setprio(1);
#pragma unroll
            for (int ds = 0; ds < 4; ++ds) {
                const char* ka_p = Kb + (kb * 32 + l31) * 128 + (((2 * ds + hi) ^ l7) << 4);
                bfrag ka = *(const bfrag*)ka_p;
                s = MFMA32(ka, qb[ds], s, 0, 0, 0);
            }
            __builtin_amdgcn_s_setprio(0);
            float e[16];
#pragma unroll
            for (int j = 0; j < 16; ++j) e[j] = fexp2(s[j]);
#pragma unroll
            for (int j = 0; j < 8; ++j) { lacc0 += e[2 * j]; lacc1 += e[2 * j + 1]; }
            unsigned u[4][2];
#pragma unroll
            for (int g = 0; g < 4; ++g) {
                u[g][0] = cvtpk(e[4 * g + 0], e[4 * g + 1]);
                u[g][1] = cvtpk(e[4 * g + 2], e[4 * g + 3]);
            }
#pragma unroll
            for (int ks = 0; ks < 2; ++ks) {
                asm("v_permlane32_swap_b32 %0, %1" : "+v"(u[2*ks][0]), "+v"(u[2*ks+1][0]));
                asm("v_permlane32_swap_b32 %0, %1" : "+v"(u[2*ks][1]), "+v"(u[2*ks+1][1]));
                uint4 fw = { u[2*ks][0], u[2*ks][1], u[2*ks+1][0], u[2*ks+1][1] };
                pf[kb * 2 + ks] = *(const bfrag*)&fw;
            }
        }

        // PV: O^T[64 d][32 q] += V^T * P^T
        __builtin_amdgcn_s_setprio(1);
#pragma unroll
        for (int db = 0; db < 2; ++db)
#pragma unroll
            for (int ks = 0; ks < 4; ++ks) {
                const char* va_p = Vb + (db * 32 + l31) * 128 + (((2 * ks + hi) ^ l7) << 4);
                bfrag va = *(const bfrag*)va_p;
                o[db] = MFMA32(va, pf[ks], o[db], 0, 0, 0);
            }
        __builtin_amdgcn_s_setprio(0);
    }
#undef STAGE
    __builtin_amdgcn_s_barrier();   // all compute done before smem overlay

    float lacc = lacc0 + lacc1;
    lacc += __shfl_xor(lacc, 32);
    if (hi == 0)
        Larr[(size_t)(sp * 16 + bh) * NN + n0 + wv * 32 + l31] = lacc;

    // epilogue: pack O' bf16, transpose via LDS, coalesced uint4 stores
    unsigned (*Osb)[36] = (unsigned(*)[36])smem;   // [128][36] u32
    {
        int row = wv * 32 + l31;
#pragma unroll
        for (int db = 0; db < 2; ++db)
#pragma unroll
            for (int g = 0; g < 4; ++g) {
                uint2 pk;
                pk.x = cvtpk(o[db][4 * g + 0], o[db][4 * g + 1]);
                pk.y = cvtpk(o[db][4 * g + 2], o[db][4 * g + 3]);
                *(uint2*)&Osb[row][16 * db + 4 * g + 2 * hi] = pk;
            }
    }
    __syncthreads();
    ushort_t* opb = Op + (size_t)sp * BCN + ((size_t)b * NN + n0) * CCH + h * HD;
    for (int idx = tid; idx < 1024; idx += 256) {
        int n = idx >> 3, s4 = idx & 7;
        *(uint4*)&opb[(size_t)n * CCH + s4 * 8] = *(const uint4*)&Osb[n][s4 * 4];
    }
}

// ---------------------------------------------------------------------------
// fuse: sum kv-splits (bf16 O') + depthwise 3x3 BN (tap-major bf16 pw2)
// -> bf16 [b][n][c]
// ---------------------------------------------------------------------------
__global__ __launch_bounds__(256)
void fuse_kernel(const ushort_t* __restrict__ Op, const float* __restrict__ Larr,
                 const ushort_t* __restrict__ Qnd,
                 const ushort_t* __restrict__ pw2, const float* __restrict__ pbias,
                 ushort_t* __restrict__ yt)
{
    const int tid = threadIdx.x;
    const int b  = blockIdx.x / 288;
    const int n0 = (blockIdx.x % 288) * 8;
    const int c8 = tid & 31, ns = tid >> 5;
    const int n  = n0 + ns;
    const int h  = c8 >> 3, c0 = c8 * 8;

    const ushort_t* o0p = Op + ((size_t)b * NN + n) * CCH + c0;
    float acc[8] = {0.f, 0.f, 0.f, 0.f, 0.f, 0.f, 0.f, 0.f};
#pragma unroll
    for (int s = 0; s < NSP; ++s) {
        uint4 u = *(const uint4*)&o0p[(size_t)s * BCN];
        acc[0] += bflo(u.x); acc[1] += bfhi(u.x);
        acc[2] += bflo(u.y); acc[3] += bfhi(u.y);
        acc[4] += bflo(u.z); acc[5] += bfhi(u.z);
        acc[6] += bflo(u.w); acc[7] += bfhi(u.w);
    }
    int mi = (b * HEADS + h) * NN + n;
    float ls = 0.f;
#pragma unroll
    for (int s = 0; s < NSP; ++s) ls += Larr[(size_t)s * 16 * NN + mi];
    float rinv = 1.0f / ls;
#pragma unroll
    for (int j = 0; j < 8; ++j) acc[j] *= rinv;

    const int x = n % WW, y = n / WW;
    const ushort_t* qb = Qnd + (size_t)(b * HEADS + h) * NN * HD + (c8 & 7) * 8;
#pragma unroll
    for (int ky = 0; ky < 3; ++ky) {
        int yy = y + ky - 1;
        if (yy < 0 || yy >= HH) continue;
#pragma unroll
        for (int kx = 0; kx < 3; ++kx) {
            int xx = x + kx - 1;
            if (xx < 0 || xx >= WW) continue;
            int np = yy * WW + xx;
            uint4 qv = *(const uint4*)&qb[(size_t)np * HD];
            uint4 w4 = *(const uint4*)&pw2[(ky * 3 + kx) * CCH + c0];
            acc[0] += bflo(qv.x) * bflo(w4.x); acc[1] += bfhi(qv.x) * bfhi(w4.x);
            acc[2] += bflo(qv.y) * bflo(w4.y); acc[3] += bfhi(qv.y) * bfhi(w4.y);
            acc[4] += bflo(qv.z) * bflo(w4.z); acc[5] += bfhi(qv.z) * bfhi(w4.z);
            acc[6] += bflo(qv.w) * bflo(w4.w); acc[7] += bfhi(qv.w) * bfhi(w4.w);
        }
    }
    float4 p0 = *(const float4*)&pbias[c0];
    float4 p1 = *(const float4*)&pbias[c0 + 4];
    acc[0] += p0.x; acc[1] += p0.y; acc[2] += p0.z; acc[3] += p0.w;
    acc[4] += p1.x; acc[5] += p1.y; acc[6] += p1.z; acc[7] += p1.w;
    uint4 u;
    u.x = cvtpk(acc[0], acc[1]); u.y = cvtpk(acc[2], acc[3]);
    u.z = cvtpk(acc[4], acc[5]); u.w = cvtpk(acc[6], acc[7]);
    *(uint4*)&yt[((size_t)b * NN + n) * CCH + c0] = u;
}

// ---------------------------------------------------------------------------
extern "C" void kernel_launch(void* const* d_in, const int* in_sizes, int n_in,
                              void* d_out, int out_size, void* d_ws, size_t ws_size,
                              hipStream_t stream) {
    char* ws = (char*)d_ws;
    ushort_t* qnd  = (ushort_t*)(ws + 0);
    ushort_t* knd  = (ushort_t*)(ws + 4718592);
    ushort_t* vcn  = (ushort_t*)(ws + 9437184);
    ushort_t* Op   = (ushort_t*)(ws + 14155776);   // bf16 [4][BCN]
    ushort_t* yt   = (ushort_t*)(ws + 4718592);    // overlays knd after attn
    float*    Larr = (float*)   (ws + 33030144);   // [4][16][NN] fp32
    ushort_t* pw2  = (ushort_t*)(ws + 33619968);   // bf16 [9][256]
    float*    pbias= (float*)   (ws + 33624576);   // fp32 [256]

    ConvP P;
    P.X0 = (const float*)d_in[0];
    P.X1 = (const float*)d_in[1];
    P.X2 = (const float*)d_in[2];
    P.T  = yt;
    P.W[0] = (const float*)d_in[3]; P.W[1] = (const float*)d_in[4];
    P.W[2] = (const float*)d_in[5]; P.W[3] = (const float*)d_in[6];
    P.G[0]  = (const float*)d_in[8];  P.Bb[0] = (const float*)d_in[9];
    P.Mm[0] = (const float*)d_in[10]; P.Vv[0] = (const float*)d_in[11];
    P.G[1]  = (const float*)d_in[12]; P.Bb[1] = (const float*)d_in[13];
    P.Mm[1] = (const float*)d_in[14]; P.Vv[1] = (const float*)d_in[15];
    P.G[2]  = (const float*)d_in[16]; P.Bb[2] = (const float*)d_in[17];
    P.Mm[2] = (const float*)d_in[18]; P.Vv[2] = (const float*)d_in[19];
    P.G[3]  = (const float*)d_in[24]; P.Bb[3] = (const float*)d_in[25];
    P.Mm[3] = (const float*)d_in[26]; P.Vv[3] = (const float*)d_in[27];
    P.pew = (const float*)d_in[7];
    P.peg = (const float*)d_in[20]; P.peb = (const float*)d_in[21];
    P.pem = (const float*)d_in[22]; P.pev = (const float*)d_in[23];
    P.pw2 = pw2; P.pbias = pbias;
    P.qnd = qnd; P.knd = knd; P.vcn = vcn; P.outf = (float*)d_out;

    conv_gemm<0><<<dim3(36, 4, 13), 512, 0, stream>>>(P);

    attn_kernel<<<dim3(18, 16, NSP), 256, 0, stream>>>(qnd, knd, vcn, Op, Larr);

    fuse_kernel<<<1152, 256, 0, stream>>>(Op, Larr, qnd, pw2, pbias, yt);

    conv_gemm<1><<<dim3(36, 4, 4), 512, 0, stream>>>(P);
}